// Round 1
// baseline (232.478 us; speedup 1.0000x reference)
//
#include <hip/hip_runtime.h>

#define ROWS 4096
#define NCOL 8192
#define THREADS 256
#define F4PT 8   // float4 per thread: 256*8*4 = 8192 elements

__global__ __launch_bounds__(THREADS, 4)
void sparsemax_kernel(const float* __restrict__ x, float* __restrict__ out) {
    const int row = blockIdx.x;
    const size_t base = (size_t)row * NCOL;
    const float4* __restrict__ xr = (const float4*)(x + base);
    float4* __restrict__ outr = (float4*)(out + base);
    const int tid = threadIdx.x;
    const int wave = tid >> 6;
    const int lane = tid & 63;

    // Load entire row into registers (coalesced float4 loads).
    float4 v[F4PT];
#pragma unroll
    for (int j = 0; j < F4PT; ++j) {
        v[j] = xr[tid + THREADS * j];
    }

    // ---- Block max ----
    float m = -INFINITY;
#pragma unroll
    for (int j = 0; j < F4PT; ++j) {
        m = fmaxf(m, fmaxf(fmaxf(v[j].x, v[j].y), fmaxf(v[j].z, v[j].w)));
    }
#pragma unroll
    for (int off = 32; off > 0; off >>= 1) {
        m = fmaxf(m, __shfl_down(m, off, 64));
    }

    __shared__ float swv[4];   // per-wave partial (max, then sum)
    __shared__ int   swk[4];   // per-wave count
    __shared__ float stau;
    __shared__ int   sk;

    if (lane == 0) swv[wave] = m;
    __syncthreads();
    if (tid == 0) {
        float mm = fmaxf(fmaxf(swv[0], swv[1]), fmaxf(swv[2], swv[3]));
        stau = mm - 1.0f;   // tau lower bound; candidate set contains true support
    }
    __syncthreads();
    float t = stau;

    // ---- Michelot fixed-point iteration (exact, terminates when support stable) ----
    int prev_k = -1;
    for (int it = 0; it < 32; ++it) {
        float s = 0.0f;
        int   k = 0;
#pragma unroll
        for (int j = 0; j < F4PT; ++j) {
            float4 q = v[j];
            if (q.x > t) { s += q.x; ++k; }
            if (q.y > t) { s += q.y; ++k; }
            if (q.z > t) { s += q.z; ++k; }
            if (q.w > t) { s += q.w; ++k; }
        }
#pragma unroll
        for (int off = 32; off > 0; off >>= 1) {
            s += __shfl_down(s, off, 64);
            k += __shfl_down(k, off, 64);
        }
        if (lane == 0) { swv[wave] = s; swk[wave] = k; }
        __syncthreads();                      // (A) partials visible
        if (tid == 0) {
            float st = swv[0] + swv[1] + swv[2] + swv[3];
            int   kt = swk[0] + swk[1] + swk[2] + swk[3];
            sk = kt;
            stau = (st - 1.0f) / (float)kt;
        }
        __syncthreads();                      // (B) stau/sk visible
        int kt = sk;
        float tn = stau;
        if (kt == prev_k) break;              // support unchanged => tau converged (exact)
        prev_k = kt;
        t = tn;
        // Safe: next iteration's shared writes happen only after all threads pass (A).
    }

    // ---- Epilogue: out = max(x - tau, 0), coalesced float4 stores ----
#pragma unroll
    for (int j = 0; j < F4PT; ++j) {
        float4 q = v[j];
        float4 r;
        r.x = fmaxf(q.x - t, 0.0f);
        r.y = fmaxf(q.y - t, 0.0f);
        r.z = fmaxf(q.z - t, 0.0f);
        r.w = fmaxf(q.w - t, 0.0f);
        outr[tid + THREADS * j] = r;
    }
}

extern "C" void kernel_launch(void* const* d_in, const int* in_sizes, int n_in,
                              void* d_out, int out_size, void* d_ws, size_t ws_size,
                              hipStream_t stream) {
    const float* x = (const float*)d_in[0];
    float* out = (float*)d_out;
    sparsemax_kernel<<<ROWS, THREADS, 0, stream>>>(x, out);
}